// Round 7
// baseline (115.246 us; speedup 1.0000x reference)
//
#include <hip/hip_runtime.h>
#include <hip/hip_bf16.h>

using u16 = unsigned short;
using u32 = unsigned int;
typedef float f32x4 __attribute__((ext_vector_type(4)));
typedef float f32x2 __attribute__((ext_vector_type(2)));
typedef __bf16 bf16x8 __attribute__((ext_vector_type(8)));

// ---- helpers ----------------------------------------------------------------
static __device__ __forceinline__ float bflo(u32 u) { return __uint_as_float(u << 16); }
static __device__ __forceinline__ float bfhi(u32 u) { return __uint_as_float(u & 0xffff0000u); }

static __device__ __forceinline__ u32 pack2(float a, float b) {
  __hip_bfloat16 ha = __float2bfloat16(a);
  __hip_bfloat16 hb = __float2bfloat16(b);
  u16 ra, rb;
  __builtin_memcpy(&ra, &ha, 2);
  __builtin_memcpy(&rb, &hb, 2);
  return (u32)ra | ((u32)rb << 16);
}

static __device__ __forceinline__ u16 f2bf(float f) {
  u32 u = __float_as_uint(f);
  u32 r = (u + 0x7fffu + ((u >> 16) & 1u)) >> 16;
  return (u16)r;
}

static __device__ __forceinline__ bf16x8 as_bf(uint4 v) {
  bf16x8 r;
  __builtin_memcpy(&r, &v, 16);
  return r;
}

// truncating pack of two blended f32 -> bf16x2, single v_perm_b32
static __device__ __forceinline__ u32 packtrunc(float lo, float hi) {
  return __builtin_amdgcn_perm(__float_as_uint(hi), __float_as_uint(lo), 0x07060302u);
}

static __device__ __forceinline__ f32x2 unpk(u32 u) {
  f32x2 r;
  r.x = bflo(u);
  r.y = bfhi(u);
  return r;
}

// 4-corner bilinear blend of 8 bf16 channels -> bf16x8 fragment (as uint4)
static __device__ __forceinline__ uint4 blend4(uint4 a, uint4 b, uint4 c, uint4 d,
                                               float w00, float w01, float w10, float w11) {
  uint4 r;
#pragma unroll
  for (int j = 0; j < 4; j++) {
    f32x2 v = unpk((&a.x)[j]) * w00;
    v += unpk((&b.x)[j]) * w01;
    v += unpk((&c.x)[j]) * w10;
    v += unpk((&d.x)[j]) * w11;
    (&r.x)[j] = packtrunc(v.x, v.y);
  }
  return r;
}

// ---- kernel 1: x [B,C,H,W] f32 -> xT [B,H,W,C] bf16 -------------------------
__global__ __launch_bounds__(256) void transpose_k(const float* __restrict__ x,
                                                   u16* __restrict__ xT) {
  const int bid = blockIdx.x;
  const int b = bid >> 6, y = bid & 63;
  const int t = threadIdx.x;
  const int cg = t >> 4;
  const int w16 = t & 15;
  const float* xp = x + ((size_t)(b * 128) * 64 + y) * 64;
  u16* op = xT + ((size_t)(b * 64 + y) * 64) * 128;
#pragma unroll
  for (int pass = 0; pass < 4; pass++) {
    int w = pass * 16 + w16;
    u32 rr[4];
#pragma unroll
    for (int jj = 0; jj < 4; jj++) {
      float a = xp[(cg * 8 + 2 * jj) * 4096 + w];
      float c = xp[(cg * 8 + 2 * jj + 1) * 4096 + w];
      rr[jj] = pack2(a, c);
    }
    uint4 r;
    r.x = rr[0]; r.y = rr[1]; r.z = rr[2]; r.w = rr[3];
    *(uint4*)(op + w * 128 + cg * 8) = r;
  }
}

// ---- kernel 2: weff in MFMA-A-fragment layout --------------------------------
// element index = ((ks*6 + nt)*64 + lane)*8 + j
//   n (=o) = nt*16 + (lane&15);  kc = (lane>>4)*8 + j
// ks: br = ks>=36, ksb = ks-36*br, tap = ksb>>2, chunk = ksb&3, c = chunk*32+kc
__global__ __launch_bounds__(256) void weff_k(const float* __restrict__ w0,
                                              const float* __restrict__ w1,
                                              const float* __restrict__ wf,
                                              u16* __restrict__ weffg) {
  const int idx = blockIdx.x * 256 + threadIdx.x;  // 221184 total
  const int j = idx & 7;
  const int l = (idx >> 3) & 63;
  const int rest = idx >> 9;       // ks*6 + nt, 0..431
  const int nt = rest % 6;
  const int ks = rest / 6;
  const int n = nt * 16 + (l & 15);
  const int kc = (l >> 4) * 8 + j;
  const int br = ks >= 36 ? 1 : 0;
  const int ksb = ks - br * 36;
  const int tap = ksb >> 2, chunk = ksb & 3;
  const int c = chunk * 32 + kc;
  float acc = 0.f;
  if (n < 84) {
    const float* w = br ? w1 : w0;
    const float* wfp = wf + n * 168 + br * 84;
    const float* wp = w + c * 9 + tap;   // stride per oc = 128*9 = 1152
#pragma unroll 4
    for (int oc = 0; oc < 84; oc++) acc += wfp[oc] * wp[oc * 1152];
  }
  weffg[idx] = f2bf(acc);
}

// ---- kernel 3: fused deform-sample + GEMM, residency-first ------------------
// 2048 blocks = (b:8 -> XCD-pinned) x (h:64) x (quarter:4). 4 waves = (br,cp)
// K-split. Wave: 16 px x 96 out x K=576, 18 phases (9 taps x 2 chunks of 32ch).
// Phase: weff(6) | blend q -> af | issue next phase's 4 gathers | 6 MFMA.
// REGISTER BUDGET IS THE POINT (r6 lesson: gfx950 unified file counts
// VGPR+AGPR together; 100+48acc=148 > 128 -> 2 waves/SIMD, occupancy stuck):
//   acc 24 (AGPR) + q 16 + weff 24 + addr/wt ~15 + misc ~25 ~= 105 <= 128
// -> 4 waves/SIMD, 4 blocks/CU, ~16 waves/CU (2x r3/r5/r6 residency).
__global__ __launch_bounds__(256, 2) void deform_main(
    const u16* __restrict__ xT, const u16* __restrict__ weffg,
    const float* __restrict__ dm0, const float* __restrict__ dm1,
    const float* __restrict__ bias, float* __restrict__ out) {
  __shared__ f32x4 red[3][6][64];   // 18 KiB

  const int t = threadIdx.x;
  const int wv = t >> 6, lane = t & 63;
  const int br = wv >> 1, cp = wv & 1;
  const int lrow = lane & 15, lg = lane >> 4;
  const int blk = blockIdx.x;
  const int b = blk & 7;
  const int rem = blk >> 3;            // 0..255
  const int h = rem & 63;
  const int px0 = (rem >> 6) * 16;     // quarter

  const u16* xb = xT + (size_t)b * 524288;
  const float* dmb = (br ? dm1 : dm0) + (size_t)b * 73728 + h * 64 + px0 + lrow;
  const u16* wbase = weffg + (size_t)(br * 36 + cp * 2) * 3072 + lane * 8;
  const int cb = cp * 64 + lg * 8;     // channel base (u16 elems) for this lane

  f32x4 acc[6];
#pragma unroll
  for (int i = 0; i < 6; i++) acc[i] = f32x4{0.f, 0.f, 0.f, 0.f};

  float w00, w01, w10, w11;
  int r0, r1, xo0, xo1;
  float dyN, dxN;
  uint4 q[4];    // 4 corners in flight (one phase ahead)

  auto tapstate = [&](int ty, int tx, float dy, float dx) {
    float pyf = (float)(h + ty - 1) + dy;
    float pxf = (float)(px0 + lrow + tx - 1) + dx;
    float y0f = floorf(pyf), x0f = floorf(pxf);
    int y0 = (int)y0f, x0 = (int)x0f;
    float wy1 = pyf - y0f, wx1 = pxf - x0f;
    float wy0 = 1.f - wy1, wx0 = 1.f - wx1;
    int y1 = y0 + 1, x1 = x0 + 1;
    wy0 *= ((u32)y0 < 64u) ? 1.f : 0.f;
    wy1 *= ((u32)y1 < 64u) ? 1.f : 0.f;
    wx0 *= ((u32)x0 < 64u) ? 1.f : 0.f;
    wx1 *= ((u32)x1 < 64u) ? 1.f : 0.f;
    w00 = wy0 * wx0; w01 = wy0 * wx1;
    w10 = wy1 * wx0; w11 = wy1 * wx1;
    int y0c = min(63, max(0, y0)), y1c = min(63, max(0, y1));
    int x0c = min(63, max(0, x0)), x1c = min(63, max(0, x1));
    r0 = y0c * 8192 + cb; r1 = y1c * 8192 + cb;
    xo0 = x0c * 128; xo1 = x1c * 128;
  };

  auto issue = [&](int co) {
    const u16* p0 = xb + r0 + co;
    const u16* p1 = xb + r1 + co;
    q[0] = *(const uint4*)(p0 + xo0);
    q[1] = *(const uint4*)(p0 + xo1);
    q[2] = *(const uint4*)(p1 + xo0);
    q[3] = *(const uint4*)(p1 + xo1);
  };

  // ---- prologue ----
  {
    float dy0 = dmb[0], dx0 = dmb[4096];
    tapstate(0, 0, dy0, dx0);
  }
  issue(0);
  dyN = dmb[2 * 4096]; dxN = dmb[3 * 4096];

#pragma unroll 1
  for (int tap = 0; tap < 9; tap++) {
#pragma unroll
    for (int c = 0; c < 2; c++) {
      const u16* wp = wbase + (size_t)(tap * 4 + c) * 3072;
      uint4 wq0 = *(const uint4*)(wp);
      uint4 wq1 = *(const uint4*)(wp + 512);
      uint4 wq2 = *(const uint4*)(wp + 1024);
      uint4 wq3 = *(const uint4*)(wp + 1536);
      uint4 wq4 = *(const uint4*)(wp + 2048);
      uint4 wq5 = *(const uint4*)(wp + 2560);

      // blend current gathers (issued one phase ago)
      uint4 a0 = blend4(q[0], q[1], q[2], q[3], w00, w01, w10, w11);

      // issue next phase's gathers (q regs now dead)
      if (c == 0) {
        issue(32);
        if (tap < 8) {
          dyN = dmb[(2 * tap + 2) * 4096];
          dxN = dmb[(2 * tap + 3) * 4096];
        }
      } else if (tap < 8) {
        int tn = tap + 1;
        int ty = (tn * 11) >> 5;     // tn/3
        int tx = tn - ty * 3;
        tapstate(ty, tx, dyN, dxN);
        issue(0);
      }

      bf16x8 af = as_bf(a0);
      __builtin_amdgcn_s_setprio(1);
      acc[0] = __builtin_amdgcn_mfma_f32_16x16x32_bf16(as_bf(wq0), af, acc[0], 0, 0, 0);
      acc[1] = __builtin_amdgcn_mfma_f32_16x16x32_bf16(as_bf(wq1), af, acc[1], 0, 0, 0);
      acc[2] = __builtin_amdgcn_mfma_f32_16x16x32_bf16(as_bf(wq2), af, acc[2], 0, 0, 0);
      acc[3] = __builtin_amdgcn_mfma_f32_16x16x32_bf16(as_bf(wq3), af, acc[3], 0, 0, 0);
      acc[4] = __builtin_amdgcn_mfma_f32_16x16x32_bf16(as_bf(wq4), af, acc[4], 0, 0, 0);
      acc[5] = __builtin_amdgcn_mfma_f32_16x16x32_bf16(as_bf(wq5), af, acc[5], 0, 0, 0);
      __builtin_amdgcn_s_setprio(0);
    }
  }

  // ---- reduce the 4 K-partials across waves, then store ----
  if (wv > 0) {
#pragma unroll
    for (int nt = 0; nt < 6; nt++) red[wv - 1][nt][lane] = acc[nt];
  }
  __syncthreads();
  if (wv == 0) {
#pragma unroll
    for (int nt = 0; nt < 6; nt++) {
#pragma unroll
      for (int r = 0; r < 3; r++) {
        f32x4 v = red[r][nt][lane];
#pragma unroll
        for (int j = 0; j < 4; j++) acc[nt][j] += v[j];
      }
    }
    float* op = out + ((size_t)b * 84 * 64 + h) * 64 + px0;
#pragma unroll
    for (int nt = 0; nt < 6; nt++) {
#pragma unroll
      for (int j = 0; j < 4; j++) {
        int o = nt * 16 + lg * 4 + j;
        if (o < 84) op[(size_t)o * 4096 + lrow] = acc[nt][j] + bias[o];
      }
    }
  }
}

// ---- launch -----------------------------------------------------------------
extern "C" void kernel_launch(void* const* d_in, const int* in_sizes, int n_in,
                              void* d_out, int out_size, void* d_ws, size_t ws_size,
                              hipStream_t stream) {
  const float* x   = (const float*)d_in[0];
  const float* dm0 = (const float*)d_in[1];
  const float* dm1 = (const float*)d_in[2];
  const float* w0  = (const float*)d_in[3];
  const float* w1  = (const float*)d_in[4];
  const float* wf  = (const float*)d_in[5];
  const float* bf  = (const float*)d_in[6];
  float* out = (float*)d_out;

  u16* xT = (u16*)d_ws;                                               // 8 MiB
  u16* weffg = (u16*)((char*)d_ws + (size_t)8 * 64 * 64 * 128 * 2);   // 432 KiB

  transpose_k<<<512, 256, 0, stream>>>(x, xT);
  weff_k<<<864, 256, 0, stream>>>(w0, w1, wf, weffg);
  deform_main<<<2048, 256, 0, stream>>>(xT, weffg, dm0, dm1, bf, out);
}

// Round 8
// 105.837 us; speedup vs baseline: 1.0889x; 1.0889x over previous
//
#include <hip/hip_runtime.h>
#include <hip/hip_bf16.h>

using u16 = unsigned short;
using u32 = unsigned int;
typedef float f32x4 __attribute__((ext_vector_type(4)));
typedef float f32x2 __attribute__((ext_vector_type(2)));
typedef __bf16 bf16x8 __attribute__((ext_vector_type(8)));
typedef u32 u32x4 __attribute__((ext_vector_type(4)));

// ---- helpers ----------------------------------------------------------------
static __device__ __forceinline__ float bflo(u32 u) { return __uint_as_float(u << 16); }
static __device__ __forceinline__ float bfhi(u32 u) { return __uint_as_float(u & 0xffff0000u); }

static __device__ __forceinline__ u32 pack2(float a, float b) {
  __hip_bfloat16 ha = __float2bfloat16(a);
  __hip_bfloat16 hb = __float2bfloat16(b);
  u16 ra, rb;
  __builtin_memcpy(&ra, &ha, 2);
  __builtin_memcpy(&rb, &hb, 2);
  return (u32)ra | ((u32)rb << 16);
}

static __device__ __forceinline__ u16 f2bf(float f) {
  u32 u = __float_as_uint(f);
  u32 r = (u + 0x7fffu + ((u >> 16) & 1u)) >> 16;
  return (u16)r;
}

static __device__ __forceinline__ bf16x8 as_bf(uint4 v) {
  bf16x8 r;
  __builtin_memcpy(&r, &v, 16);
  return r;
}
static __device__ __forceinline__ bf16x8 as_bf4(u32x4 v) {
  bf16x8 r;
  __builtin_memcpy(&r, &v, 16);
  return r;
}

// non-temporal 16B load (evict-first: keep L1 for the gather neighborhood)
static __device__ __forceinline__ u32x4 ntload(const u16* p) {
  return __builtin_nontemporal_load((const u32x4*)p);
}

// truncating pack of two blended f32 -> bf16x2, single v_perm_b32
static __device__ __forceinline__ u32 packtrunc(float lo, float hi) {
  return __builtin_amdgcn_perm(__float_as_uint(hi), __float_as_uint(lo), 0x07060302u);
}

static __device__ __forceinline__ f32x2 unpk(u32 u) {
  f32x2 r;
  r.x = bflo(u);
  r.y = bfhi(u);
  return r;
}

// 4-corner bilinear blend of 8 bf16 channels -> bf16x8 fragment (as uint4)
static __device__ __forceinline__ uint4 blend4(uint4 a, uint4 b, uint4 c, uint4 d,
                                               float w00, float w01, float w10, float w11) {
  uint4 r;
#pragma unroll
  for (int j = 0; j < 4; j++) {
    f32x2 v = unpk((&a.x)[j]) * w00;
    v += unpk((&b.x)[j]) * w01;
    v += unpk((&c.x)[j]) * w10;
    v += unpk((&d.x)[j]) * w11;
    (&r.x)[j] = packtrunc(v.x, v.y);
  }
  return r;
}

// ---- kernel 1: x [B,C,H,W] f32 -> xT [B,H,W,C] bf16 -------------------------
__global__ __launch_bounds__(256) void transpose_k(const float* __restrict__ x,
                                                   u16* __restrict__ xT) {
  const int bid = blockIdx.x;
  const int b = bid >> 6, y = bid & 63;
  const int t = threadIdx.x;
  const int cg = t >> 4;
  const int w16 = t & 15;
  const float* xp = x + ((size_t)(b * 128) * 64 + y) * 64;
  u16* op = xT + ((size_t)(b * 64 + y) * 64) * 128;
#pragma unroll
  for (int pass = 0; pass < 4; pass++) {
    int w = pass * 16 + w16;
    u32 rr[4];
#pragma unroll
    for (int jj = 0; jj < 4; jj++) {
      float a = xp[(cg * 8 + 2 * jj) * 4096 + w];
      float c = xp[(cg * 8 + 2 * jj + 1) * 4096 + w];
      rr[jj] = pack2(a, c);
    }
    uint4 r;
    r.x = rr[0]; r.y = rr[1]; r.z = rr[2]; r.w = rr[3];
    *(uint4*)(op + w * 128 + cg * 8) = r;
  }
}

// ---- kernel 2: weff in MFMA-A-fragment layout --------------------------------
// element index = ((ks*6 + nt)*64 + lane)*8 + j
//   n (=o) = nt*16 + (lane&15);  kc = (lane>>4)*8 + j
// ks: br = ks>=36, ksb = ks-36*br, tap = ksb>>2, chunk = ksb&3, c = chunk*32+kc
__global__ __launch_bounds__(256) void weff_k(const float* __restrict__ w0,
                                              const float* __restrict__ w1,
                                              const float* __restrict__ wf,
                                              u16* __restrict__ weffg) {
  const int idx = blockIdx.x * 256 + threadIdx.x;  // 221184 total
  const int j = idx & 7;
  const int l = (idx >> 3) & 63;
  const int rest = idx >> 9;       // ks*6 + nt, 0..431
  const int nt = rest % 6;
  const int ks = rest / 6;
  const int n = nt * 16 + (l & 15);
  const int kc = (l >> 4) * 8 + j;
  const int br = ks >= 36 ? 1 : 0;
  const int ksb = ks - br * 36;
  const int tap = ksb >> 2, chunk = ksb & 3;
  const int c = chunk * 32 + kc;
  float acc = 0.f;
  if (n < 84) {
    const float* w = br ? w1 : w0;
    const float* wfp = wf + n * 168 + br * 84;
    const float* wp = w + c * 9 + tap;   // stride per oc = 128*9 = 1152
#pragma unroll 4
    for (int oc = 0; oc < 84; oc++) acc += wfp[oc] * wp[oc * 1152];
  }
  weffg[idx] = f2bf(acc);
}

// ---- kernel 3: fused deform-sample + GEMM ------------------------------------
// 512 blocks = (b:8 -> XCD-pinned L2) x (h:64). 4 waves = (br:2, cp:2) K-split.
// Wave: 64 px x 96 out x K=576, 18 phases (9 taps x 2 chunks of 32 ch).
// r8 changes vs r5 (line/miss-rate model: L1-miss concurrency is the wall):
//  1. weff double-buffered in regs (ping-pong over the unrolled c-phases):
//     loads issued one full phase early -> no per-phase weff-dependent stall.
//  2. weff loads non-temporal -> weff stops evicting the gather lines from L1.
//  3. boustrophedon tap order (0,1,2,5,4,3,6,7,8): consecutive taps move 1 px
//     -> tap t's x1/y1 lines frequently == tap t+1's x0/y0 lines (L1 hits).
// Register budget: r5 measured 188 total; +24 (2nd weff set) ~= 212 <= 256
// cap of (256,1). WRITE_SIZE is the spill canary (10.75 MB == clean).
__global__ __launch_bounds__(256, 1) void deform_main(
    const u16* __restrict__ xT, const u16* __restrict__ weffg,
    const float* __restrict__ dm0, const float* __restrict__ dm1,
    const float* __restrict__ bias, float* __restrict__ out) {
  __shared__ f32x4 red[2][6][4][64];   // 48 KiB

  const int t = threadIdx.x;
  const int wv = t >> 6, lane = t & 63;
  const int br = wv >> 1, cp = wv & 1;
  const int lrow = lane & 15, lg = lane >> 4;
  const int blk = blockIdx.x;
  const int b = blk & 7, h = blk >> 3;

  const u16* xb = xT + (size_t)b * 524288;
  const float* dmb = (br ? dm1 : dm0) + (size_t)b * 73728 + h * 64 + lrow;
  const u16* wbase = weffg + (size_t)(br * 36 + cp * 2) * 3072 + lane * 8;
  const int cb = cp * 64 + lg * 8;     // channel base (u16 elems) for this lane

  f32x4 acc[6][4];
#pragma unroll
  for (int i = 0; i < 6; i++)
#pragma unroll
    for (int f = 0; f < 4; f++) acc[i][f] = f32x4{0.f, 0.f, 0.f, 0.f};

  float w00a[4], w01a[4], w10a[4], w11a[4];
  int r0a[4], r1a[4], xo0a[4], xo1a[4];
  float dyN[4], dxN[4];
  uint4 qa[8], qb[8];    // frags 0,1 / frags 2,3 — 4 corners each, in flight
  u32x4 wA0, wA1, wA2, wA3, wA4, wA5;   // weff ping (chunk 0 of current tap)
  u32x4 wB0, wB1, wB2, wB3, wB4, wB5;   // weff pong (chunk 1 / next tap c0)

  auto tapstate = [&](int f, int ty, int tx, float dy, float dx) {
    float pyf = (float)(h + ty - 1) + dy;
    float pxf = (float)(f * 16 + lrow + tx - 1) + dx;
    float y0f = floorf(pyf), x0f = floorf(pxf);
    int y0 = (int)y0f, x0 = (int)x0f;
    float wy1 = pyf - y0f, wx1 = pxf - x0f;
    float wy0 = 1.f - wy1, wx0 = 1.f - wx1;
    int y1 = y0 + 1, x1 = x0 + 1;
    wy0 *= ((u32)y0 < 64u) ? 1.f : 0.f;
    wy1 *= ((u32)y1 < 64u) ? 1.f : 0.f;
    wx0 *= ((u32)x0 < 64u) ? 1.f : 0.f;
    wx1 *= ((u32)x1 < 64u) ? 1.f : 0.f;
    w00a[f] = wy0 * wx0; w01a[f] = wy0 * wx1;
    w10a[f] = wy1 * wx0; w11a[f] = wy1 * wx1;
    int y0c = min(63, max(0, y0)), y1c = min(63, max(0, y1));
    int x0c = min(63, max(0, x0)), x1c = min(63, max(0, x1));
    r0a[f] = y0c * 8192 + cb; r1a[f] = y1c * 8192 + cb;
    xo0a[f] = x0c * 128; xo1a[f] = x1c * 128;
  };

  auto issueA = [&](int co) {
#pragma unroll
    for (int f = 0; f < 2; f++) {
      const u16* p0 = xb + r0a[f] + co;
      const u16* p1 = xb + r1a[f] + co;
      qa[f * 4 + 0] = *(const uint4*)(p0 + xo0a[f]);
      qa[f * 4 + 1] = *(const uint4*)(p0 + xo1a[f]);
      qa[f * 4 + 2] = *(const uint4*)(p1 + xo0a[f]);
      qa[f * 4 + 3] = *(const uint4*)(p1 + xo1a[f]);
    }
  };
  auto issueB = [&](int co) {
#pragma unroll
    for (int f = 0; f < 2; f++) {
      int g = f + 2;
      const u16* p0 = xb + r0a[g] + co;
      const u16* p1 = xb + r1a[g] + co;
      qb[f * 4 + 0] = *(const uint4*)(p0 + xo0a[g]);
      qb[f * 4 + 1] = *(const uint4*)(p0 + xo1a[g]);
      qb[f * 4 + 2] = *(const uint4*)(p1 + xo0a[g]);
      qb[f * 4 + 3] = *(const uint4*)(p1 + xo1a[g]);
    }
  };

  // ---- prologue: tap 0 state, issue phase-0 gathers + weff, dm(tap 1) ----
#pragma unroll
  for (int f = 0; f < 4; f++) {
    dyN[f] = dmb[f * 16];
    dxN[f] = dmb[4096 + f * 16];
  }
#pragma unroll
  for (int f = 0; f < 4; f++) tapstate(f, 0, 0, dyN[f], dxN[f]);
  issueA(0);
  issueB(0);
#pragma unroll
  for (int f = 0; f < 4; f++) {
    dyN[f] = dmb[2 * 4096 + f * 16];
    dxN[f] = dmb[3 * 4096 + f * 16];
  }
  {
    const u16* wp = wbase;   // (tap0, c0)
    wA0 = ntload(wp);        wA1 = ntload(wp + 512);  wA2 = ntload(wp + 1024);
    wA3 = ntload(wp + 1536); wA4 = ntload(wp + 2048); wA5 = ntload(wp + 2560);
  }

#pragma unroll 1
  for (int tt = 0; tt < 9; tt++) {
    const int tap = (tt >= 3 && tt < 6) ? 8 - tt : tt;       // boustrophedon
    const int tnx = tt + 1;
    const int tapn = (tnx >= 3 && tnx < 6) ? 8 - tnx : tnx;  // next (tt<8)

    // ======== phase c=0: consume wA, current gathers ========
    {
      const u16* wpB = wbase + (size_t)(tap * 4 + 1) * 3072;
      wB0 = ntload(wpB);        wB1 = ntload(wpB + 512);  wB2 = ntload(wpB + 1024);
      wB3 = ntload(wpB + 1536); wB4 = ntload(wpB + 2048); wB5 = ntload(wpB + 2560);

      uint4 a0 = blend4(qa[0], qa[1], qa[2], qa[3], w00a[0], w01a[0], w10a[0], w11a[0]);
      uint4 a1 = blend4(qa[4], qa[5], qa[6], qa[7], w00a[1], w01a[1], w10a[1], w11a[1]);
      bf16x8 af0 = as_bf(a0), af1 = as_bf(a1);
      __builtin_amdgcn_s_setprio(1);
      acc[0][0] = __builtin_amdgcn_mfma_f32_16x16x32_bf16(as_bf4(wA0), af0, acc[0][0], 0, 0, 0);
      acc[1][0] = __builtin_amdgcn_mfma_f32_16x16x32_bf16(as_bf4(wA1), af0, acc[1][0], 0, 0, 0);
      acc[2][0] = __builtin_amdgcn_mfma_f32_16x16x32_bf16(as_bf4(wA2), af0, acc[2][0], 0, 0, 0);
      acc[3][0] = __builtin_amdgcn_mfma_f32_16x16x32_bf16(as_bf4(wA3), af0, acc[3][0], 0, 0, 0);
      acc[4][0] = __builtin_amdgcn_mfma_f32_16x16x32_bf16(as_bf4(wA4), af0, acc[4][0], 0, 0, 0);
      acc[5][0] = __builtin_amdgcn_mfma_f32_16x16x32_bf16(as_bf4(wA5), af0, acc[5][0], 0, 0, 0);
      acc[0][1] = __builtin_amdgcn_mfma_f32_16x16x32_bf16(as_bf4(wA0), af1, acc[0][1], 0, 0, 0);
      acc[1][1] = __builtin_amdgcn_mfma_f32_16x16x32_bf16(as_bf4(wA1), af1, acc[1][1], 0, 0, 0);
      acc[2][1] = __builtin_amdgcn_mfma_f32_16x16x32_bf16(as_bf4(wA2), af1, acc[2][1], 0, 0, 0);
      acc[3][1] = __builtin_amdgcn_mfma_f32_16x16x32_bf16(as_bf4(wA3), af1, acc[3][1], 0, 0, 0);
      acc[4][1] = __builtin_amdgcn_mfma_f32_16x16x32_bf16(as_bf4(wA4), af1, acc[4][1], 0, 0, 0);
      acc[5][1] = __builtin_amdgcn_mfma_f32_16x16x32_bf16(as_bf4(wA5), af1, acc[5][1], 0, 0, 0);
      __builtin_amdgcn_s_setprio(0);

      uint4 a2 = blend4(qb[0], qb[1], qb[2], qb[3], w00a[2], w01a[2], w10a[2], w11a[2]);
      uint4 a3 = blend4(qb[4], qb[5], qb[6], qb[7], w00a[3], w01a[3], w10a[3], w11a[3]);

      // gathers for (tap, c=1); dm for next tap
      issueA(32);
      issueB(32);
      if (tt < 8) {
#pragma unroll
        for (int f = 0; f < 4; f++) {
          dyN[f] = dmb[(2 * tapn) * 4096 + f * 16];
          dxN[f] = dmb[(2 * tapn + 1) * 4096 + f * 16];
        }
      }

      bf16x8 af2 = as_bf(a2), af3 = as_bf(a3);
      __builtin_amdgcn_s_setprio(1);
      acc[0][2] = __builtin_amdgcn_mfma_f32_16x16x32_bf16(as_bf4(wA0), af2, acc[0][2], 0, 0, 0);
      acc[1][2] = __builtin_amdgcn_mfma_f32_16x16x32_bf16(as_bf4(wA1), af2, acc[1][2], 0, 0, 0);
      acc[2][2] = __builtin_amdgcn_mfma_f32_16x16x32_bf16(as_bf4(wA2), af2, acc[2][2], 0, 0, 0);
      acc[3][2] = __builtin_amdgcn_mfma_f32_16x16x32_bf16(as_bf4(wA3), af2, acc[3][2], 0, 0, 0);
      acc[4][2] = __builtin_amdgcn_mfma_f32_16x16x32_bf16(as_bf4(wA4), af2, acc[4][2], 0, 0, 0);
      acc[5][2] = __builtin_amdgcn_mfma_f32_16x16x32_bf16(as_bf4(wA5), af2, acc[5][2], 0, 0, 0);
      acc[0][3] = __builtin_amdgcn_mfma_f32_16x16x32_bf16(as_bf4(wA0), af3, acc[0][3], 0, 0, 0);
      acc[1][3] = __builtin_amdgcn_mfma_f32_16x16x32_bf16(as_bf4(wA1), af3, acc[1][3], 0, 0, 0);
      acc[2][3] = __builtin_amdgcn_mfma_f32_16x16x32_bf16(as_bf4(wA2), af3, acc[2][3], 0, 0, 0);
      acc[3][3] = __builtin_amdgcn_mfma_f32_16x16x32_bf16(as_bf4(wA3), af3, acc[3][3], 0, 0, 0);
      acc[4][3] = __builtin_amdgcn_mfma_f32_16x16x32_bf16(as_bf4(wA4), af3, acc[4][3], 0, 0, 0);
      acc[5][3] = __builtin_amdgcn_mfma_f32_16x16x32_bf16(as_bf4(wA5), af3, acc[5][3], 0, 0, 0);
      __builtin_amdgcn_s_setprio(0);
    }

    // ======== phase c=1: consume wB, gathers issued in c=0 ========
    {
      if (tt < 8) {
        const u16* wpA = wbase + (size_t)(tapn * 4) * 3072;
        wA0 = ntload(wpA);        wA1 = ntload(wpA + 512);  wA2 = ntload(wpA + 1024);
        wA3 = ntload(wpA + 1536); wA4 = ntload(wpA + 2048); wA5 = ntload(wpA + 2560);
      }

      uint4 a0 = blend4(qa[0], qa[1], qa[2], qa[3], w00a[0], w01a[0], w10a[0], w11a[0]);
      uint4 a1 = blend4(qa[4], qa[5], qa[6], qa[7], w00a[1], w01a[1], w10a[1], w11a[1]);
      bf16x8 af0 = as_bf(a0), af1 = as_bf(a1);
      __builtin_amdgcn_s_setprio(1);
      acc[0][0] = __builtin_amdgcn_mfma_f32_16x16x32_bf16(as_bf4(wB0), af0, acc[0][0], 0, 0, 0);
      acc[1][0] = __builtin_amdgcn_mfma_f32_16x16x32_bf16(as_bf4(wB1), af0, acc[1][0], 0, 0, 0);
      acc[2][0] = __builtin_amdgcn_mfma_f32_16x16x32_bf16(as_bf4(wB2), af0, acc[2][0], 0, 0, 0);
      acc[3][0] = __builtin_amdgcn_mfma_f32_16x16x32_bf16(as_bf4(wB3), af0, acc[3][0], 0, 0, 0);
      acc[4][0] = __builtin_amdgcn_mfma_f32_16x16x32_bf16(as_bf4(wB4), af0, acc[4][0], 0, 0, 0);
      acc[5][0] = __builtin_amdgcn_mfma_f32_16x16x32_bf16(as_bf4(wB5), af0, acc[5][0], 0, 0, 0);
      acc[0][1] = __builtin_amdgcn_mfma_f32_16x16x32_bf16(as_bf4(wB0), af1, acc[0][1], 0, 0, 0);
      acc[1][1] = __builtin_amdgcn_mfma_f32_16x16x32_bf16(as_bf4(wB1), af1, acc[1][1], 0, 0, 0);
      acc[2][1] = __builtin_amdgcn_mfma_f32_16x16x32_bf16(as_bf4(wB2), af1, acc[2][1], 0, 0, 0);
      acc[3][1] = __builtin_amdgcn_mfma_f32_16x16x32_bf16(as_bf4(wB3), af1, acc[3][1], 0, 0, 0);
      acc[4][1] = __builtin_amdgcn_mfma_f32_16x16x32_bf16(as_bf4(wB4), af1, acc[4][1], 0, 0, 0);
      acc[5][1] = __builtin_amdgcn_mfma_f32_16x16x32_bf16(as_bf4(wB5), af1, acc[5][1], 0, 0, 0);
      __builtin_amdgcn_s_setprio(0);

      uint4 a2 = blend4(qb[0], qb[1], qb[2], qb[3], w00a[2], w01a[2], w10a[2], w11a[2]);
      uint4 a3 = blend4(qb[4], qb[5], qb[6], qb[7], w00a[3], w01a[3], w10a[3], w11a[3]);

      if (tt < 8) {
        int ty = (tapn * 11) >> 5;     // tapn/3
        int tx = tapn - ty * 3;
#pragma unroll
        for (int f = 0; f < 4; f++) tapstate(f, ty, tx, dyN[f], dxN[f]);
        issueA(0);
        issueB(0);
      }

      bf16x8 af2 = as_bf(a2), af3 = as_bf(a3);
      __builtin_amdgcn_s_setprio(1);
      acc[0][2] = __builtin_amdgcn_mfma_f32_16x16x32_bf16(as_bf4(wB0), af2, acc[0][2], 0, 0, 0);
      acc[1][2] = __builtin_amdgcn_mfma_f32_16x16x32_bf16(as_bf4(wB1), af2, acc[1][2], 0, 0, 0);
      acc[2][2] = __builtin_amdgcn_mfma_f32_16x16x32_bf16(as_bf4(wB2), af2, acc[2][2], 0, 0, 0);
      acc[3][2] = __builtin_amdgcn_mfma_f32_16x16x32_bf16(as_bf4(wB3), af2, acc[3][2], 0, 0, 0);
      acc[4][2] = __builtin_amdgcn_mfma_f32_16x16x32_bf16(as_bf4(wB4), af2, acc[4][2], 0, 0, 0);
      acc[5][2] = __builtin_amdgcn_mfma_f32_16x16x32_bf16(as_bf4(wB5), af2, acc[5][2], 0, 0, 0);
      acc[0][3] = __builtin_amdgcn_mfma_f32_16x16x32_bf16(as_bf4(wB0), af3, acc[0][3], 0, 0, 0);
      acc[1][3] = __builtin_amdgcn_mfma_f32_16x16x32_bf16(as_bf4(wB1), af3, acc[1][3], 0, 0, 0);
      acc[2][3] = __builtin_amdgcn_mfma_f32_16x16x32_bf16(as_bf4(wB2), af3, acc[2][3], 0, 0, 0);
      acc[3][3] = __builtin_amdgcn_mfma_f32_16x16x32_bf16(as_bf4(wB3), af3, acc[3][3], 0, 0, 0);
      acc[4][3] = __builtin_amdgcn_mfma_f32_16x16x32_bf16(as_bf4(wB4), af3, acc[4][3], 0, 0, 0);
      acc[5][3] = __builtin_amdgcn_mfma_f32_16x16x32_bf16(as_bf4(wB5), af3, acc[5][3], 0, 0, 0);
      __builtin_amdgcn_s_setprio(0);
    }
  }

  // ---- reduce the 4 K-partials across waves, then store ----
  if (wv >= 2) {
#pragma unroll
    for (int nt = 0; nt < 6; nt++)
#pragma unroll
      for (int f = 0; f < 4; f++) red[wv - 2][nt][f][lane] = acc[nt][f];
  }
  __syncthreads();
  if (wv < 2) {
#pragma unroll
    for (int nt = 0; nt < 6; nt++)
#pragma unroll
      for (int f = 0; f < 4; f++) {
        f32x4 v = red[wv][nt][f][lane];
#pragma unroll
        for (int j = 0; j < 4; j++) acc[nt][f][j] += v[j];
      }
  }
  if (wv == 1) {
#pragma unroll
    for (int nt = 0; nt < 6; nt++)
#pragma unroll
      for (int f = 0; f < 4; f++) red[1][nt][f][lane] = acc[nt][f];
  }
  __syncthreads();
  if (wv == 0) {
    float* op = out + ((size_t)b * 84 * 64 + h) * 64;
#pragma unroll
    for (int nt = 0; nt < 6; nt++)
#pragma unroll
      for (int f = 0; f < 4; f++) {
        f32x4 v = red[1][nt][f][lane];
#pragma unroll
        for (int j = 0; j < 4; j++) acc[nt][f][j] += v[j];
      }
#pragma unroll
    for (int nt = 0; nt < 6; nt++)
#pragma unroll
      for (int j = 0; j < 4; j++) {
        int o = nt * 16 + lg * 4 + j;
        if (o < 84) {
          float bv = bias[o];
#pragma unroll
          for (int f = 0; f < 4; f++)
            op[(size_t)o * 4096 + f * 16 + lrow] = acc[nt][f][j] + bv;
        }
      }
  }
}

// ---- launch -----------------------------------------------------------------
extern "C" void kernel_launch(void* const* d_in, const int* in_sizes, int n_in,
                              void* d_out, int out_size, void* d_ws, size_t ws_size,
                              hipStream_t stream) {
  const float* x   = (const float*)d_in[0];
  const float* dm0 = (const float*)d_in[1];
  const float* dm1 = (const float*)d_in[2];
  const float* w0  = (const float*)d_in[3];
  const float* w1  = (const float*)d_in[4];
  const float* wf  = (const float*)d_in[5];
  const float* bf  = (const float*)d_in[6];
  float* out = (float*)d_out;

  u16* xT = (u16*)d_ws;                                               // 8 MiB
  u16* weffg = (u16*)((char*)d_ws + (size_t)8 * 64 * 64 * 128 * 2);   // 432 KiB

  transpose_k<<<512, 256, 0, stream>>>(x, xT);
  weff_k<<<864, 256, 0, stream>>>(w0, w1, wf, weffg);
  deform_main<<<512, 256, 0, stream>>>(xT, weffg, dm0, dm1, bf, out);
}

// Round 10
// 68.654 us; speedup vs baseline: 1.6787x; 1.5416x over previous
//
#include <hip/hip_runtime.h>
#include <hip/hip_bf16.h>

using u16 = unsigned short;
using u32 = unsigned int;
typedef float f32x4 __attribute__((ext_vector_type(4)));
typedef float f32x2 __attribute__((ext_vector_type(2)));
typedef __bf16 bf16x8 __attribute__((ext_vector_type(8)));
typedef u32 u32x4 __attribute__((ext_vector_type(4)));

// ---- helpers ----------------------------------------------------------------
static __device__ __forceinline__ float bflo(u32 u) { return __uint_as_float(u << 16); }
static __device__ __forceinline__ float bfhi(u32 u) { return __uint_as_float(u & 0xffff0000u); }

static __device__ __forceinline__ u32 pack2(float a, float b) {
  __hip_bfloat16 ha = __float2bfloat16(a);
  __hip_bfloat16 hb = __float2bfloat16(b);
  u16 ra, rb;
  __builtin_memcpy(&ra, &ha, 2);
  __builtin_memcpy(&rb, &hb, 2);
  return (u32)ra | ((u32)rb << 16);
}

static __device__ __forceinline__ u16 f2bf(float f) {
  u32 u = __float_as_uint(f);
  u32 r = (u + 0x7fffu + ((u >> 16) & 1u)) >> 16;
  return (u16)r;
}

static __device__ __forceinline__ bf16x8 as_bf(uint4 v) {
  bf16x8 r;
  __builtin_memcpy(&r, &v, 16);
  return r;
}

// truncating pack of two blended f32 -> bf16x2, single v_perm_b32
static __device__ __forceinline__ u32 packtrunc(float lo, float hi) {
  return __builtin_amdgcn_perm(__float_as_uint(hi), __float_as_uint(lo), 0x07060302u);
}

static __device__ __forceinline__ f32x2 unpk(u32 u) {
  f32x2 r;
  r.x = bflo(u);
  r.y = bfhi(u);
  return r;
}

// 4-corner bilinear blend of 8 bf16 channels -> bf16x8 fragment (as uint4)
static __device__ __forceinline__ uint4 blend4(uint4 a, uint4 b, uint4 c, uint4 d,
                                               float w00, float w01, float w10, float w11) {
  uint4 r;
#pragma unroll
  for (int j = 0; j < 4; j++) {
    f32x2 v = unpk((&a.x)[j]) * w00;
    v += unpk((&b.x)[j]) * w01;
    v += unpk((&c.x)[j]) * w10;
    v += unpk((&d.x)[j]) * w11;
    (&r.x)[j] = packtrunc(v.x, v.y);
  }
  return r;
}

// ---- kernel 1: x [B,C,H,W] f32 -> xT [B,H,W,C] bf16 -------------------------
__global__ __launch_bounds__(256) void transpose_k(const float* __restrict__ x,
                                                   u16* __restrict__ xT) {
  const int bid = blockIdx.x;
  const int b = bid >> 6, y = bid & 63;
  const int t = threadIdx.x;
  const int cg = t >> 4;
  const int w16 = t & 15;
  const float* xp = x + ((size_t)(b * 128) * 64 + y) * 64;
  u16* op = xT + ((size_t)(b * 64 + y) * 64) * 128;
#pragma unroll
  for (int pass = 0; pass < 4; pass++) {
    int w = pass * 16 + w16;
    u32 rr[4];
#pragma unroll
    for (int jj = 0; jj < 4; jj++) {
      float a = xp[(cg * 8 + 2 * jj) * 4096 + w];
      float c = xp[(cg * 8 + 2 * jj + 1) * 4096 + w];
      rr[jj] = pack2(a, c);
    }
    uint4 r;
    r.x = rr[0]; r.y = rr[1]; r.z = rr[2]; r.w = rr[3];
    *(uint4*)(op + w * 128 + cg * 8) = r;
  }
}

// ---- kernel 2: weff in MFMA-A-fragment layout --------------------------------
__global__ __launch_bounds__(256) void weff_k(const float* __restrict__ w0,
                                              const float* __restrict__ w1,
                                              const float* __restrict__ wf,
                                              u16* __restrict__ weffg) {
  const int idx = blockIdx.x * 256 + threadIdx.x;  // 221184 total
  const int j = idx & 7;
  const int l = (idx >> 3) & 63;
  const int rest = idx >> 9;       // ks*6 + nt, 0..431
  const int nt = rest % 6;
  const int ks = rest / 6;
  const int n = nt * 16 + (l & 15);
  const int kc = (l >> 4) * 8 + j;
  const int br = ks >= 36 ? 1 : 0;
  const int ksb = ks - br * 36;
  const int tap = ksb >> 2, chunk = ksb & 3;
  const int c = chunk * 32 + kc;
  float acc = 0.f;
  if (n < 84) {
    const float* w = br ? w1 : w0;
    const float* wfp = wf + n * 168 + br * 84;
    const float* wp = w + c * 9 + tap;   // stride per oc = 128*9 = 1152
#pragma unroll 4
    for (int oc = 0; oc < 84; oc++) acc += wfp[oc] * wp[oc * 1152];
  }
  weffg[idx] = f2bf(acc);
}

// ---- kernel 3: LDS-resident row-window deform-sample + GEMM -----------------
// 512 blocks = (b:8 -> XCD) x (h:64), 512 threads (8 waves).
// Wave wv: pxh = wv>>2 (32-px half), br = (wv>>1)&1, cp = wv&1 (K quarter).
// Stage rows [h-4, h+4] of xT (9 x 64px x 128ch bf16) into LDS once; all
// bilinear corner reads become ds_read_b128 (LGKM pipe, no TA/L1-miss path).
// LDS layout (16B units): [(row*16 + slot)*65 + x], slot = ch/8, +1 pad per 64.
// Out-of-window rows (P ~ 1.3e-3/sample) fall back to predicated global loads.
// r10 fix vs r9: fallback channel base is cp*64 (slot = cp*8+c*4+lg -> channel
// cp*64+c*32+lg*8); r9 used cp*128 -> cp=1 waves read the next pixel's data.
__global__ __launch_bounds__(512, 1) void deform_main(
    const u16* __restrict__ xT, const u16* __restrict__ weffg,
    const float* __restrict__ dm0, const float* __restrict__ dm1,
    const float* __restrict__ bias, float* __restrict__ out) {
  __shared__ uint4 ldsbuf[9360];   // 9 rows * 16 slots * 65 * 16B = 146.25 KiB

  const int t = threadIdx.x;
  const int wv = t >> 6, lane = t & 63;
  const int pxh = wv >> 2, br = (wv >> 1) & 1, cp = wv & 1;
  const int lrow = lane & 15, lg = lane >> 4;
  const int blk = blockIdx.x;
  const int b = blk & 7, h = blk >> 3;
  const int px0 = pxh * 32;

  const u16* xb = xT + (size_t)b * 524288;

  // ---- stage rows [h-4, h+4] into LDS (coalesced 16B, 18 iters/thread) ----
#pragma unroll
  for (int k = 0; k < 18; k++) {
    int u = t + (k << 9);          // < 9216
    int i = u >> 10;               // window row 0..8
    int ul = u & 1023;             // x*16 + slot
    int ysr = min(63, max(0, h - 4 + i));
    uint4 v = *(const uint4*)(xb + ysr * 8192 + ul * 8);
    int s = ul & 15, x = ul >> 4;
    ldsbuf[(i * 16 + s) * 65 + x] = v;
  }
  __syncthreads();

  const float* dmb = (br ? dm1 : dm0) + (size_t)b * 73728 + h * 64 + px0 + lrow;
  const u16* wbase = weffg + (size_t)(br * 36 + cp * 2) * 3072 + lane * 8;

  f32x4 acc[6][2];
#pragma unroll
  for (int i = 0; i < 6; i++)
#pragma unroll
    for (int f = 0; f < 2; f++) acc[i][f] = f32x4{0.f, 0.f, 0.f, 0.f};

  float w00a[2], w01a[2], w10a[2], w11a[2];
  int x0a[2], x1a[2], yw0a[2], yw1a[2];   // yw*: window-relative rows (may be OOW)
  float dyN[2], dxN[2];
  uint4 q[16];                            // [c][f][corner] in flight (1 tap ahead)
  uint4 wA0, wA1, wA2, wA3, wA4, wA5;     // weff ping
  uint4 wB0, wB1, wB2, wB3, wB4, wB5;     // weff pong

  auto tapstate = [&](int f, int ty, int tx, float dy, float dx) {
    float pyf = (float)(h + ty - 1) + dy;
    float pxf = (float)(px0 + f * 16 + lrow + tx - 1) + dx;
    float y0f = floorf(pyf), x0f = floorf(pxf);
    int y0 = (int)y0f, x0 = (int)x0f;
    float wy1 = pyf - y0f, wx1 = pxf - x0f;
    float wy0 = 1.f - wy1, wx0 = 1.f - wx1;
    int y1 = y0 + 1, x1 = x0 + 1;
    wy0 *= ((u32)y0 < 64u) ? 1.f : 0.f;
    wy1 *= ((u32)y1 < 64u) ? 1.f : 0.f;
    wx0 *= ((u32)x0 < 64u) ? 1.f : 0.f;
    wx1 *= ((u32)x1 < 64u) ? 1.f : 0.f;
    w00a[f] = wy0 * wx0; w01a[f] = wy0 * wx1;
    w10a[f] = wy1 * wx0; w11a[f] = wy1 * wx1;
    int y0c = min(63, max(0, y0)), y1c = min(63, max(0, y1));
    x0a[f] = min(63, max(0, x0));
    x1a[f] = min(63, max(0, x1));
    yw0a[f] = y0c - h + 4;                // in-window iff 0..8
    yw1a[f] = y1c - h + 4;
  };

  // issue all 16 ds_read corners for the current tap
  auto issue_lds = [&]() {
#pragma unroll
    for (int c = 0; c < 2; c++) {
      int slot = cp * 8 + c * 4 + lg;
#pragma unroll
      for (int f = 0; f < 2; f++) {
        int y0w = min(8, max(0, yw0a[f]));
        int y1w = min(8, max(0, yw1a[f]));
        int b0 = (y0w * 16 + slot) * 65;
        int b1 = (y1w * 16 + slot) * 65;
        q[c * 8 + f * 4 + 0] = ldsbuf[b0 + x0a[f]];
        q[c * 8 + f * 4 + 1] = ldsbuf[b0 + x1a[f]];
        q[c * 8 + f * 4 + 2] = ldsbuf[b1 + x0a[f]];
        q[c * 8 + f * 4 + 3] = ldsbuf[b1 + x1a[f]];
      }
    }
  };

  // rare out-of-window fallback: predicated global corner loads
  auto oow_fix = [&]() {
    bool bad = ((u32)yw0a[0] > 8u) | ((u32)yw1a[0] > 8u) |
               ((u32)yw0a[1] > 8u) | ((u32)yw1a[1] > 8u);
    if (__any(bad)) {
#pragma unroll
      for (int f = 0; f < 2; f++) {
        if ((u32)yw0a[f] > 8u) {
          const u16* p = xb + (yw0a[f] + h - 4) * 8192 + cp * 64 + lg * 8;
#pragma unroll
          for (int c = 0; c < 2; c++) {
            q[c * 8 + f * 4 + 0] = *(const uint4*)(p + c * 32 + x0a[f] * 128);
            q[c * 8 + f * 4 + 1] = *(const uint4*)(p + c * 32 + x1a[f] * 128);
          }
        }
        if ((u32)yw1a[f] > 8u) {
          const u16* p = xb + (yw1a[f] + h - 4) * 8192 + cp * 64 + lg * 8;
#pragma unroll
          for (int c = 0; c < 2; c++) {
            q[c * 8 + f * 4 + 2] = *(const uint4*)(p + c * 32 + x0a[f] * 128);
            q[c * 8 + f * 4 + 3] = *(const uint4*)(p + c * 32 + x1a[f] * 128);
          }
        }
      }
    }
  };

  // ---- prologue: tap 0 state + reads, dm(tap1), weff step0 ----
  {
    float dy0 = dmb[0], dx0 = dmb[4096];
    float dy1 = dmb[16], dx1 = dmb[4096 + 16];
    tapstate(0, 0, 0, dy0, dx0);
    tapstate(1, 0, 0, dy1, dx1);
  }
  issue_lds();
  oow_fix();
  dyN[0] = dmb[2 * 4096];      dxN[0] = dmb[3 * 4096];
  dyN[1] = dmb[2 * 4096 + 16]; dxN[1] = dmb[3 * 4096 + 16];
  {
    const u16* wp = wbase;   // (tap0, c0)
    wA0 = *(const uint4*)(wp);        wA1 = *(const uint4*)(wp + 512);
    wA2 = *(const uint4*)(wp + 1024); wA3 = *(const uint4*)(wp + 1536);
    wA4 = *(const uint4*)(wp + 2048); wA5 = *(const uint4*)(wp + 2560);
  }

#pragma unroll 1
  for (int tap = 0; tap < 9; tap++) {
    // ---- chunk c=0: consume wA ----
    {
      const u16* wpB = wbase + (size_t)(tap * 4 + 1) * 3072;
      wB0 = *(const uint4*)(wpB);        wB1 = *(const uint4*)(wpB + 512);
      wB2 = *(const uint4*)(wpB + 1024); wB3 = *(const uint4*)(wpB + 1536);
      wB4 = *(const uint4*)(wpB + 2048); wB5 = *(const uint4*)(wpB + 2560);

      uint4 a0 = blend4(q[0], q[1], q[2], q[3], w00a[0], w01a[0], w10a[0], w11a[0]);
      uint4 a1 = blend4(q[4], q[5], q[6], q[7], w00a[1], w01a[1], w10a[1], w11a[1]);
      bf16x8 af0 = as_bf(a0), af1 = as_bf(a1);
      __builtin_amdgcn_s_setprio(1);
      acc[0][0] = __builtin_amdgcn_mfma_f32_16x16x32_bf16(as_bf(wA0), af0, acc[0][0], 0, 0, 0);
      acc[1][0] = __builtin_amdgcn_mfma_f32_16x16x32_bf16(as_bf(wA1), af0, acc[1][0], 0, 0, 0);
      acc[2][0] = __builtin_amdgcn_mfma_f32_16x16x32_bf16(as_bf(wA2), af0, acc[2][0], 0, 0, 0);
      acc[3][0] = __builtin_amdgcn_mfma_f32_16x16x32_bf16(as_bf(wA3), af0, acc[3][0], 0, 0, 0);
      acc[4][0] = __builtin_amdgcn_mfma_f32_16x16x32_bf16(as_bf(wA4), af0, acc[4][0], 0, 0, 0);
      acc[5][0] = __builtin_amdgcn_mfma_f32_16x16x32_bf16(as_bf(wA5), af0, acc[5][0], 0, 0, 0);
      acc[0][1] = __builtin_amdgcn_mfma_f32_16x16x32_bf16(as_bf(wA0), af1, acc[0][1], 0, 0, 0);
      acc[1][1] = __builtin_amdgcn_mfma_f32_16x16x32_bf16(as_bf(wA1), af1, acc[1][1], 0, 0, 0);
      acc[2][1] = __builtin_amdgcn_mfma_f32_16x16x32_bf16(as_bf(wA2), af1, acc[2][1], 0, 0, 0);
      acc[3][1] = __builtin_amdgcn_mfma_f32_16x16x32_bf16(as_bf(wA3), af1, acc[3][1], 0, 0, 0);
      acc[4][1] = __builtin_amdgcn_mfma_f32_16x16x32_bf16(as_bf(wA4), af1, acc[4][1], 0, 0, 0);
      acc[5][1] = __builtin_amdgcn_mfma_f32_16x16x32_bf16(as_bf(wA5), af1, acc[5][1], 0, 0, 0);
      __builtin_amdgcn_s_setprio(0);
    }

    // ---- chunk c=1: consume wB ----
    {
      if (tap < 8) {
        const u16* wpA = wbase + (size_t)((tap + 1) * 4) * 3072;
        wA0 = *(const uint4*)(wpA);        wA1 = *(const uint4*)(wpA + 512);
        wA2 = *(const uint4*)(wpA + 1024); wA3 = *(const uint4*)(wpA + 1536);
        wA4 = *(const uint4*)(wpA + 2048); wA5 = *(const uint4*)(wpA + 2560);
      }

      uint4 a2 = blend4(q[8], q[9], q[10], q[11], w00a[0], w01a[0], w10a[0], w11a[0]);
      uint4 a3 = blend4(q[12], q[13], q[14], q[15], w00a[1], w01a[1], w10a[1], w11a[1]);

      // next tap: state + ds-issue (q now dead), dm prefetch 2 taps ahead
      if (tap < 8) {
        int tn = tap + 1;
        int ty = (tn * 11) >> 5;     // tn/3
        int tx = tn - ty * 3;
        tapstate(0, ty, tx, dyN[0], dxN[0]);
        tapstate(1, ty, tx, dyN[1], dxN[1]);
        issue_lds();
        oow_fix();
        if (tap < 7) {
          dyN[0] = dmb[(2 * tn + 2) * 4096];      dxN[0] = dmb[(2 * tn + 3) * 4096];
          dyN[1] = dmb[(2 * tn + 2) * 4096 + 16]; dxN[1] = dmb[(2 * tn + 3) * 4096 + 16];
        }
      }

      bf16x8 af2 = as_bf(a2), af3 = as_bf(a3);
      __builtin_amdgcn_s_setprio(1);
      acc[0][0] = __builtin_amdgcn_mfma_f32_16x16x32_bf16(as_bf(wB0), af2, acc[0][0], 0, 0, 0);
      acc[1][0] = __builtin_amdgcn_mfma_f32_16x16x32_bf16(as_bf(wB1), af2, acc[1][0], 0, 0, 0);
      acc[2][0] = __builtin_amdgcn_mfma_f32_16x16x32_bf16(as_bf(wB2), af2, acc[2][0], 0, 0, 0);
      acc[3][0] = __builtin_amdgcn_mfma_f32_16x16x32_bf16(as_bf(wB3), af2, acc[3][0], 0, 0, 0);
      acc[4][0] = __builtin_amdgcn_mfma_f32_16x16x32_bf16(as_bf(wB4), af2, acc[4][0], 0, 0, 0);
      acc[5][0] = __builtin_amdgcn_mfma_f32_16x16x32_bf16(as_bf(wB5), af2, acc[5][0], 0, 0, 0);
      acc[0][1] = __builtin_amdgcn_mfma_f32_16x16x32_bf16(as_bf(wB0), af3, acc[0][1], 0, 0, 0);
      acc[1][1] = __builtin_amdgcn_mfma_f32_16x16x32_bf16(as_bf(wB1), af3, acc[1][1], 0, 0, 0);
      acc[2][1] = __builtin_amdgcn_mfma_f32_16x16x32_bf16(as_bf(wB2), af3, acc[2][1], 0, 0, 0);
      acc[3][1] = __builtin_amdgcn_mfma_f32_16x16x32_bf16(as_bf(wB3), af3, acc[3][1], 0, 0, 0);
      acc[4][1] = __builtin_amdgcn_mfma_f32_16x16x32_bf16(as_bf(wB4), af3, acc[4][1], 0, 0, 0);
      acc[5][1] = __builtin_amdgcn_mfma_f32_16x16x32_bf16(as_bf(wB5), af3, acc[5][1], 0, 0, 0);
      __builtin_amdgcn_s_setprio(0);
    }
  }

  // ---- reduce the 4 K-partials per px-half (reuse staging LDS), store ----
  __syncthreads();                       // all LDS gather reads done
  const int sub = wv & 3;                // br*2+cp
  const int rbase = pxh * 2304;          // uint4 units; 2*2304 = 4608 <= 9360
  if (sub > 0) {
#pragma unroll
    for (int nt = 0; nt < 6; nt++)
#pragma unroll
      for (int f = 0; f < 2; f++) {
        uint4 v;
        __builtin_memcpy(&v, &acc[nt][f], 16);
        ldsbuf[rbase + ((sub - 1) * 12 + nt * 2 + f) * 64 + lane] = v;
      }
  }
  __syncthreads();
  if (sub == 0) {
#pragma unroll
    for (int nt = 0; nt < 6; nt++)
#pragma unroll
      for (int f = 0; f < 2; f++) {
#pragma unroll
        for (int r = 0; r < 3; r++) {
          uint4 v = ldsbuf[rbase + (r * 12 + nt * 2 + f) * 64 + lane];
          f32x4 fv;
          __builtin_memcpy(&fv, &v, 16);
#pragma unroll
          for (int j = 0; j < 4; j++) acc[nt][f][j] += fv[j];
        }
      }
    float* op = out + ((size_t)b * 84 * 64 + h) * 64 + px0;
#pragma unroll
    for (int nt = 0; nt < 6; nt++)
#pragma unroll
      for (int j = 0; j < 4; j++) {
        int o = nt * 16 + lg * 4 + j;
        if (o < 84) {
          float bv = bias[o];
#pragma unroll
          for (int f = 0; f < 2; f++)
            op[(size_t)o * 4096 + f * 16 + lrow] = acc[nt][f][j] + bv;
        }
      }
  }
}

// ---- launch -----------------------------------------------------------------
extern "C" void kernel_launch(void* const* d_in, const int* in_sizes, int n_in,
                              void* d_out, int out_size, void* d_ws, size_t ws_size,
                              hipStream_t stream) {
  const float* x   = (const float*)d_in[0];
  const float* dm0 = (const float*)d_in[1];
  const float* dm1 = (const float*)d_in[2];
  const float* w0  = (const float*)d_in[3];
  const float* w1  = (const float*)d_in[4];
  const float* wf  = (const float*)d_in[5];
  const float* bf  = (const float*)d_in[6];
  float* out = (float*)d_out;

  u16* xT = (u16*)d_ws;                                               // 8 MiB
  u16* weffg = (u16*)((char*)d_ws + (size_t)8 * 64 * 64 * 128 * 2);   // 432 KiB

  transpose_k<<<512, 256, 0, stream>>>(x, xT);
  weff_k<<<864, 256, 0, stream>>>(w0, w1, wf, weffg);
  deform_main<<<512, 512, 0, stream>>>(xT, weffg, dm0, dm1, bf, out);
}